// Round 20
// baseline (536.572 us; speedup 1.0000x reference)
//
#include <hip/hip_runtime.h>

#define B 4
#define C 64
#define T 256
#define A 4096
#define RC 264        // residual columns = T + 8
#define PW 260        // fm position stride (257 real, 3 sentinel)
#define NITER 32
#define NBLK 256      // blocks in step kernels
#define ATB 16        // atoms owned per step block
#define WSTR 44       // wpad channel stride (floats): cg*12 mod 32 all-distinct
#define WROW 2816     // 64*WSTR

// ---------------- workspace layout (bytes) ----------------
#define WS_DN     0            // A*512 f32            = 8,388,608
#define WS_RES    8388608      // B*C*RC f32           =   270,336
#define WS_RECON  8658944      // B*C*RC f32           =   270,336
#define WS_FM     8929280      // B*A*PW f32           = 17,039,360
#define WS_PARTS  25968640     // parts[2][4][256] u64 = 16,384
#define WS_RMAX   25985024     // rmax_g[4][4096] u64  = 131,072

typedef unsigned long long u64;

// LDS bank swizzle: XOR word-addr bits 2-4 with bits 5-7 (16B-chunk preserving)
#define SW(w) ((w) ^ ((((w) >> 5) & 7) << 2))

// pack: [monotone f32:32][~key:21][11 zero bits]
__device__ __forceinline__ u64 packmax21(float v, unsigned key) {
    unsigned u = __float_as_uint(v);
    u = (u & 0x80000000u) ? ~u : (u | 0x80000000u);
    return ((u64)u << 32) | ((u64)(0x1FFFFFu - key) << 11);
}
__device__ __forceinline__ void decode21(u64 m, int* atom, int* pos, float* val) {
    const unsigned key = 0x1FFFFFu - (unsigned)((m >> 11) & 0x1FFFFFu);
    unsigned uv = (unsigned)(m >> 32);
    uv = (uv & 0x80000000u) ? (uv & 0x7FFFFFFFu) : ~uv;
    *atom = (int)(key / PW); *pos = (int)(key % PW); *val = __uint_as_float(uv);
}

// ---------------- K1: unit-norm dict + init res/recon/fm edges ----------------
__global__ void k_init(const float* __restrict__ x, const float* __restrict__ d,
                       float* __restrict__ dn, float* __restrict__ res,
                       float* __restrict__ recon, float* __restrict__ fm) {
    const int t = threadIdx.x;
    {
        const int atom = blockIdx.x * 4 + (t >> 6);
        const int lane = t & 63;
        const float* src = d + atom * 512;
        float4 v0 = ((const float4*)src)[lane * 2];
        float4 v1 = ((const float4*)src)[lane * 2 + 1];
        float s = v0.x*v0.x + v0.y*v0.y + v0.z*v0.z + v0.w*v0.w
                + v1.x*v1.x + v1.y*v1.y + v1.z*v1.z + v1.w*v1.w;
        #pragma unroll
        for (int off = 32; off; off >>= 1) s += __shfl_xor(s, off);
        const float denom = sqrtf(s) + 1e-8f;
        float* dst = dn + atom * 512;
        float4 o0 = make_float4(v0.x/denom, v0.y/denom, v0.z/denom, v0.w/denom);
        float4 o1 = make_float4(v1.x/denom, v1.y/denom, v1.z/denom, v1.w/denom);
        ((float4*)dst)[lane * 2]     = o0;
        ((float4*)dst)[lane * 2 + 1] = o1;
    }
    const int tid = blockIdx.x * blockDim.x + t;
    const int nth = gridDim.x * blockDim.x;
    for (int i = tid; i < B * C * RC; i += nth) {
        const int col = i % RC;
        const int bc  = i / RC;
        res[i]   = (col < T) ? x[bc * T + col] : 0.0f;
        recon[i] = 0.0f;
    }
    for (int i = tid; i < B * A; i += nth) {
        float* row = fm + (long)i * PW;
        row[256] = 0.0f;
        row[257] = -1e30f; row[258] = -1e30f; row[259] = -1e30f;
    }
}

// ---------------- K2: full correlation + fused row-max scan (v4) ----------------
// grid (A/64, B), 256 threads. thread = (slot=t>>4 -> 4 atoms, pg=t&15 -> 16 pos).
// Dict LDS layout [cc][as][k] (+SW): dk broadcast groups land on distinct banks.
// Per cc per thread: 14 b128 reads / 512 FMA -> FMA-bound.
__global__ __launch_bounds__(256) void k_conv(const float* __restrict__ res,
                                              const float* __restrict__ dn,
                                              float* __restrict__ fm,
                                              u64* __restrict__ rmax_g,
                                              u64* __restrict__ parts0) {
    __shared__ __align__(16) float lr[16 * 264];      // swizzled residual chunk
    __shared__ __align__(16) float ld[16 * 64 * 8];   // swizzled dict [cc][as][k]
    __shared__ u64 rr[64];
    const int ck = blockIdx.x;           // 64-atom chunk
    const int b  = blockIdx.y;
    const int a0 = ck * 64;
    const int t  = threadIdx.x;
    const int slot = t >> 4;             // 0..15 -> atoms slot*4 .. slot*4+3
    const int pg   = t & 15;             // positions p0 = pg*16
    const int p0   = pg * 16;

    float acc[4][16] = {};

    for (int cb = 0; cb < 4; ++cb) {
        const float* rsrc = res + (b * C + cb * 16) * RC;
        for (int i = t; i < 16 * 264; i += 256) lr[SW(i)] = rsrc[i];
        const float* dsrc = dn + (long)a0 * 512 + cb * 128;
        for (int i = t; i < 64 * 128; i += 256) {
            const int as = i >> 7, rem = i & 127;        // rem = cc*8 + k
            const int cc = rem >> 3, k = rem & 7;
            ld[SW(cc * 512 + as * 8 + k)] = dsrc[(long)as * 512 + rem];
        }
        __syncthreads();

        for (int cc = 0; cc < 16; ++cc) {
            float rv[24];
            const int base = cc * 264 + p0;
            #pragma unroll
            for (int j = 0; j < 6; ++j)
                *(float4*)(rv + 4 * j) = *(const float4*)&lr[SW(base + 4 * j)];
            #pragma unroll
            for (int ai = 0; ai < 4; ++ai) {
                const int dbase = cc * 512 + (slot * 4 + ai) * 8;
                float dk[8];
                *(float4*)(dk)     = *(const float4*)&ld[SW(dbase)];
                *(float4*)(dk + 4) = *(const float4*)&ld[SW(dbase + 4)];
                #pragma unroll
                for (int pi = 0; pi < 16; ++pi)
                    #pragma unroll
                    for (int kk = 0; kk < 8; ++kk)
                        acc[ai][pi] = fmaf(rv[pi + kk], dk[kk], acc[ai][pi]);
            }
        }
        __syncthreads();
    }

    // fm stores + per-row packed maxima
    u64 pm[4];
    #pragma unroll
    for (int ai = 0; ai < 4; ++ai) {
        const int row = a0 + slot * 4 + ai;
        float* outp = fm + ((long)b * A + row) * PW + p0;
        *(float4*)(outp)      = *(const float4*)&acc[ai][0];
        *(float4*)(outp + 4)  = *(const float4*)&acc[ai][4];
        *(float4*)(outp + 8)  = *(const float4*)&acc[ai][8];
        *(float4*)(outp + 12) = *(const float4*)&acc[ai][12];
        const unsigned rkey = (unsigned)(row * PW);
        u64 m = 0ull;
        #pragma unroll
        for (int i = 0; i < 16; ++i) {
            const u64 q = packmax21(acc[ai][i], rkey + p0 + i);
            if (q > m) m = q;
        }
        pm[ai] = m;
    }
    #pragma unroll
    for (int off = 1; off <= 8; off <<= 1) {
        #pragma unroll
        for (int ai = 0; ai < 4; ++ai) {
            u64 o = __shfl_xor(pm[ai], off);
            if (o > pm[ai]) pm[ai] = o;
        }
    }
    if (pg == 0) {
        #pragma unroll
        for (int ai = 0; ai < 4; ++ai) {
            const int row = a0 + slot * 4 + ai;
            u64 m = pm[ai];
            const u64 z = packmax21(0.0f, (unsigned)(row * PW) + 256);  // col 256 = 0
            if (z > m) m = z;
            rmax_g[(size_t)b * A + row] = m;
            rr[slot * 4 + ai] = m;
        }
    }
    __syncthreads();
    if (t < 4) {
        u64 m = rr[t * 16];
        #pragma unroll
        for (int i = 1; i < 16; ++i) if (rr[t * 16 + i] > m) m = rr[t * 16 + i];
        parts0[b * 256 + ck * 4 + t] = m;
    }
}

// ---------------- K5: one matching-pursuit iteration (one graph node) ----------------
__global__ __launch_bounds__(512) void k_step(const float* __restrict__ dn,
                                              float* __restrict__ recon,
                                              float* __restrict__ fm,
                                              u64* __restrict__ rmax_g,
                                              const u64* __restrict__ pin,
                                              u64* __restrict__ pout) {
    __shared__ __align__(16) float wpad[4][WROW];   // winner rows, stride-44 channels
    __shared__ float g[ATB][4][17];                 // Gram values (padded)
    __shared__ u64 rmax[4][ATB];
    __shared__ int sflag[64];
    __shared__ int   watom[4], wpos[4];
    __shared__ float wval[4];

    const int bk = blockIdx.x, a0 = bk * ATB, t = threadIdx.x;
    const int wv = t >> 6, ln = t & 63;
    const int a_ = t >> 5, tt = t & 31, bb_ = tt & 3, cg = tt >> 2;
    const int row = t >> 3, kk8 = t & 7, r_ai = row & 15, r_b = row >> 4;
    float* frow = fm + ((long)r_b * A + a0 + r_ai) * PW;
    const unsigned rkey = (unsigned)((a0 + r_ai) * PW);

    // own atom channels in registers: channel c = j*8+cg of atom a0+a_
    float own[8][8];
    {
        const float* s = dn + (long)(a0 + a_) * 512 + cg * 8;
        #pragma unroll
        for (int j = 0; j < 8; ++j) {
            *(float4*)&own[j][0] = *(const float4*)(s + j * 64);
            *(float4*)&own[j][4] = *(const float4*)(s + j * 64 + 4);
        }
    }
    for (int i = t; i < 4 * WROW; i += 512) ((float*)wpad)[i] = 0.0f;

    // ---- phase 1: winner reduce (waves 0-3) + rmax load (wave 4) ----
    if (wv < 4) {
        const u64* pb = pin + wv * 256 + ln * 4;
        u64 m0 = pb[0], m1 = pb[1], m2 = pb[2], m3 = pb[3];
        if (m1 > m0) m0 = m1;
        if (m3 > m2) m2 = m3;
        if (m2 > m0) m0 = m2;
        #pragma unroll
        for (int off = 1; off <= 32; off <<= 1) {
            u64 o = __shfl_xor(m0, off);
            if (o > m0) m0 = o;
        }
        if (ln == 0) decode21(m0, &watom[wv], &wpos[wv], &wval[wv]);
    } else if (wv == 4) {
        rmax[ln >> 4][ln & 15] = rmax_g[(size_t)(ln >> 4) * A + a0 + (ln & 15)];
    }
    __syncthreads();

    // ---- commit recon (blocks 4-7, b = bk-4) ----
    if (bk >= 4 && bk < 8) {
        const int b = bk - 4;
        const float cv = wval[b];
        const float* dw = dn + (long)watom[b] * 512;
        recon[(long)(b * C + (t >> 3)) * RC + wpos[b] + (t & 7)] += cv * dw[t];
    }

    // ---- write winner rows into wpad (data slots [8..15] of each 44-row) ----
    for (int i = t; i < 4 * 512; i += 512) {
        const int b = i >> 9, r = i & 511;
        wpad[b][(r >> 3) * WSTR + 8 + (r & 7)] = dn[(long)watom[b] * 512 + r];
    }
    __syncthreads();

    // ---- Gram: own (regs) x wpad -> g[a][bb][15] ----
    {
        float acc[15];
        #pragma unroll
        for (int i = 0; i < 15; ++i) acc[i] = 0.0f;
        #pragma unroll
        for (int j = 0; j < 8; ++j) {
            const float* wp = &wpad[bb_][(j * 8 + cg) * WSTR];
            float wr[24];
            *(float4*)(wr)      = *(const float4*)(wp);
            *(float4*)(wr + 4)  = *(const float4*)(wp + 4);
            *(float4*)(wr + 8)  = *(const float4*)(wp + 8);
            *(float4*)(wr + 12) = *(const float4*)(wp + 12);
            *(float4*)(wr + 16) = *(const float4*)(wp + 16);
            *(float4*)(wr + 20) = *(const float4*)(wp + 20);
            #pragma unroll
            for (int di = 0; di < 15; ++di)
                #pragma unroll
                for (int k = 0; k < 8; ++k)
                    acc[di] = fmaf(own[j][k], wr[15 + k - di], acc[di]);
        }
        #pragma unroll
        for (int di = 0; di < 15; ++di) {
            acc[di] += __shfl_xor(acc[di], 4);
            acc[di] += __shfl_xor(acc[di], 8);
            acc[di] += __shfl_xor(acc[di], 16);
        }
        if (cg == 0) {
            #pragma unroll
            for (int di = 0; di < 15; ++di) g[a_][bb_][di] = acc[di];
        }
    }
    __syncthreads();

    // ---- window update + winmax (8 threads per row) ----
    {
        const int q = wpos[r_b];
        const float val = wval[r_b];
        u64 wm = 0ull;
        #pragma unroll
        for (int h = 0; h < 2; ++h) {
            const int di = kk8 + h * 8;
            if (di < 15) {
                const int p = q + 7 - di;
                if (p >= 0 && p <= 256) {
                    const float nv = frow[p] - val * g[r_ai][r_b][di];
                    frow[p] = nv;
                    const u64 pm = packmax21(nv, rkey + p);
                    if (pm > wm) wm = pm;
                }
            }
        }
        #pragma unroll
        for (int off = 1; off <= 4; off <<= 1) {
            u64 o = __shfl_xor(wm, off);
            if (o > wm) wm = o;
        }
        if (kk8 == 0) {
            const u64 old = rmax[r_b][r_ai];
            const unsigned okey = 0x1FFFFFu - (unsigned)((old >> 11) & 0x1FFFFFu);
            const int opos = (int)(okey % PW);
            if (opos >= q - 7 && opos <= q + 7) {
                sflag[row] = 1;
            } else {
                sflag[row] = 0;
                rmax[r_b][r_ai] = (old > wm) ? old : wm;
            }
        }
    }
    __syncthreads();

    // ---- conditional full row rescan ----
    if (sflag[row]) {
        u64 m = 0ull;
        #pragma unroll
        for (int i = 0; i <= 8; ++i) {
            const int idx4 = kk8 + i * 8;
            if (idx4 < 65) {
                const float4 v = ((const float4*)frow)[idx4];
                const unsigned e = rkey + idx4 * 4;
                u64 q0 = packmax21(v.x, e);
                u64 q1 = packmax21(v.y, e + 1);
                u64 q2 = packmax21(v.z, e + 2);
                u64 q3 = packmax21(v.w, e + 3);
                if (q1 > q0) q0 = q1;
                if (q3 > q2) q2 = q3;
                if (q2 > q0) q0 = q2;
                if (q0 > m)  m = q0;
            }
        }
        #pragma unroll
        for (int off = 1; off <= 4; off <<= 1) {
            u64 o = __shfl_xor(m, off);
            if (o > m) m = o;
        }
        if (kk8 == 0) rmax[r_b][r_ai] = m;
    }
    __syncthreads();

    // ---- publish partials for next kernel + rmax write-back ----
    if (wv == 0) {
        const int b_ = ln >> 4, ai_ = ln & 15;
        u64 m = rmax[b_][ai_];
        #pragma unroll
        for (int off = 1; off <= 8; off <<= 1) {
            u64 o = __shfl_xor(m, off);
            if (o > m) m = o;
        }
        if (ai_ == 0) pout[b_ * 256 + bk] = m;
    } else if (wv == 1) {
        rmax_g[(size_t)(ln >> 4) * A + a0 + (ln & 15)] = rmax[ln >> 4][ln & 15];
    }
}

// ---------------- K6: final iteration — winner + commit + output copy ----------------
__global__ __launch_bounds__(512) void k_last(const float* __restrict__ dn,
                                              float* __restrict__ recon,
                                              const u64* __restrict__ pin,
                                              float* __restrict__ out) {
    __shared__ int s_atom, s_pos;
    __shared__ float s_val;
    const int b = blockIdx.x, t = threadIdx.x;
    const int wv = t >> 6, ln = t & 63;
    if (wv == 0) {
        const u64* pb = pin + b * 256 + ln * 4;
        u64 m0 = pb[0], m1 = pb[1], m2 = pb[2], m3 = pb[3];
        if (m1 > m0) m0 = m1;
        if (m3 > m2) m2 = m3;
        if (m2 > m0) m0 = m2;
        #pragma unroll
        for (int off = 1; off <= 32; off <<= 1) {
            u64 o = __shfl_xor(m0, off);
            if (o > m0) m0 = o;
        }
        if (ln == 0) decode21(m0, &s_atom, &s_pos, &s_val);
    }
    __syncthreads();
    recon[(long)(b * C + (t >> 3)) * RC + s_pos + (t & 7)] += s_val * dn[(long)s_atom * 512 + t];
    __syncthreads();
    for (int i = t; i < C * T / 4; i += 512) {
        const int c = i >> 6, t4 = i & 63;
        ((float4*)out)[b * 4096 + i] = *(const float4*)&recon[(long)(b * C + c) * RC + t4 * 4];
    }
}

extern "C" void kernel_launch(void* const* d_in, const int* in_sizes, int n_in,
                              void* d_out, int out_size, void* d_ws, size_t ws_size,
                              hipStream_t stream) {
    const float* x = (const float*)d_in[0];
    const float* d = (const float*)d_in[1];
    char* ws = (char*)d_ws;
    float* dn     = (float*)(ws + WS_DN);
    float* res    = (float*)(ws + WS_RES);
    float* recon  = (float*)(ws + WS_RECON);
    float* fm     = (float*)(ws + WS_FM);
    u64*   parts  = (u64*)(ws + WS_PARTS);
    u64*   rmax_g = (u64*)(ws + WS_RMAX);
    float* out    = (float*)d_out;
    u64* p0 = parts;
    u64* p1 = parts + 1024;

    hipLaunchKernelGGL(k_init, dim3(1024), dim3(256), 0, stream, x, d, dn, res, recon, fm);
    hipLaunchKernelGGL(k_conv, dim3(A / 64, B), dim3(256), 0, stream, res, dn, fm, rmax_g, p0);

    for (int it = 0; it < NITER - 1; ++it) {
        u64* pi = (it & 1) ? p1 : p0;
        u64* po = (it & 1) ? p0 : p1;
        hipLaunchKernelGGL(k_step, dim3(NBLK), dim3(512), 0, stream,
                           dn, recon, fm, rmax_g, pi, po);
    }
    // step 30 (even) wrote p1 — the final winner table
    hipLaunchKernelGGL(k_last, dim3(B), dim3(512), 0, stream, dn, recon, p1, out);
}

// Round 21
// 519.989 us; speedup vs baseline: 1.0319x; 1.0319x over previous
//
#include <hip/hip_runtime.h>

#define B 4
#define C 64
#define T 256
#define A 4096
#define RC 264        // residual columns = T + 8
#define PW 260        // fm position stride (257 real, 3 sentinel)
#define NITER 32
#define NBLK 256      // blocks in step kernels
#define ATB 16        // atoms owned per step block
#define WSTR 44       // wpad channel stride (floats): cg*12 mod 32 all-distinct
#define WROW 2816     // 64*WSTR

// ---------------- workspace layout (bytes) ----------------
#define WS_DN     0            // A*512 f32            = 8,388,608
#define WS_RES    8388608      // B*C*RC f32           =   270,336
#define WS_RECON  8658944      // B*C*RC f32           =   270,336
#define WS_FM     8929280      // B*A*PW f32           = 17,039,360
#define WS_PARTS  25968640     // parts[2][4][256] u64 = 16,384
#define WS_RMAX   25985024     // rmax_g[4][4096] u64  = 131,072

typedef unsigned long long u64;

// LDS bank swizzle: XOR word-addr bits 2-4 with bits 5-7 (16B-chunk preserving)
#define SW(w) ((w) ^ ((((w) >> 5) & 7) << 2))

// pack: [monotone f32:32][~key:21][11 zero bits]
__device__ __forceinline__ u64 packmax21(float v, unsigned key) {
    unsigned u = __float_as_uint(v);
    u = (u & 0x80000000u) ? ~u : (u | 0x80000000u);
    return ((u64)u << 32) | ((u64)(0x1FFFFFu - key) << 11);
}
__device__ __forceinline__ void decode21(u64 m, int* atom, int* pos, float* val) {
    const unsigned key = 0x1FFFFFu - (unsigned)((m >> 11) & 0x1FFFFFu);
    unsigned uv = (unsigned)(m >> 32);
    uv = (uv & 0x80000000u) ? (uv & 0x7FFFFFFFu) : ~uv;
    *atom = (int)(key / PW); *pos = (int)(key % PW); *val = __uint_as_float(uv);
}

// ---------------- K1: unit-norm dict + init res/recon/fm edges ----------------
__global__ void k_init(const float* __restrict__ x, const float* __restrict__ d,
                       float* __restrict__ dn, float* __restrict__ res,
                       float* __restrict__ recon, float* __restrict__ fm) {
    const int t = threadIdx.x;
    {
        const int atom = blockIdx.x * 4 + (t >> 6);
        const int lane = t & 63;
        const float* src = d + atom * 512;
        float4 v0 = ((const float4*)src)[lane * 2];
        float4 v1 = ((const float4*)src)[lane * 2 + 1];
        float s = v0.x*v0.x + v0.y*v0.y + v0.z*v0.z + v0.w*v0.w
                + v1.x*v1.x + v1.y*v1.y + v1.z*v1.z + v1.w*v1.w;
        #pragma unroll
        for (int off = 32; off; off >>= 1) s += __shfl_xor(s, off);
        const float denom = sqrtf(s) + 1e-8f;
        float* dst = dn + atom * 512;
        float4 o0 = make_float4(v0.x/denom, v0.y/denom, v0.z/denom, v0.w/denom);
        float4 o1 = make_float4(v1.x/denom, v1.y/denom, v1.z/denom, v1.w/denom);
        ((float4*)dst)[lane * 2]     = o0;
        ((float4*)dst)[lane * 2 + 1] = o1;
    }
    const int tid = blockIdx.x * blockDim.x + t;
    const int nth = gridDim.x * blockDim.x;
    for (int i = tid; i < B * C * RC; i += nth) {
        const int col = i % RC;
        const int bc  = i / RC;
        res[i]   = (col < T) ? x[bc * T + col] : 0.0f;
        recon[i] = 0.0f;
    }
    for (int i = tid; i < B * A; i += nth) {
        float* row = fm + (long)i * PW;
        row[256] = 0.0f;
        row[257] = -1e30f; row[258] = -1e30f; row[259] = -1e30f;
    }
}

// ---------------- K2: full correlation + fused row-max scan (v5) ----------------
// grid (A/32, B), 256 threads. thread = (slot=t>>4 -> 2 atoms, pg=t&15 -> 16 pos).
// R19 tiling (2 blocks/CU) + R20 dict layout [cc][as][k]: dk broadcast groups on
// disjoint bank spans. Per cc: 10 b128 / 256 FMA at 8 waves/CU.
__global__ __launch_bounds__(256) void k_conv(const float* __restrict__ res,
                                              const float* __restrict__ dn,
                                              float* __restrict__ fm,
                                              u64* __restrict__ rmax_g,
                                              u64* __restrict__ parts0) {
    __shared__ __align__(16) float lr[16 * 264];      // swizzled residual chunk
    __shared__ __align__(16) float ld[16 * 32 * 8];   // swizzled dict [cc][as][k]
    __shared__ u64 rr[32];
    const int ck = blockIdx.x;           // 32-atom chunk
    const int b  = blockIdx.y;
    const int a0 = ck * 32;
    const int t  = threadIdx.x;
    const int slot = t >> 4;             // 0..15 -> atoms slot*2, slot*2+1
    const int pg   = t & 15;             // positions p0 = pg*16
    const int p0   = pg * 16;

    float acc[2][16] = {};

    for (int cb = 0; cb < 4; ++cb) {
        const float* rsrc = res + (b * C + cb * 16) * RC;
        for (int i = t; i < 16 * 264; i += 256) lr[SW(i)] = rsrc[i];
        const float* dsrc = dn + (long)a0 * 512 + cb * 128;
        for (int i = t; i < 32 * 128; i += 256) {
            const int as = i >> 7, rem = i & 127;        // rem = cc*8 + k
            const int cc = rem >> 3, k = rem & 7;
            ld[SW(cc * 256 + as * 8 + k)] = dsrc[(long)as * 512 + rem];
        }
        __syncthreads();

        for (int cc = 0; cc < 16; ++cc) {
            float rv[24];
            const int base = cc * 264 + p0;
            #pragma unroll
            for (int j = 0; j < 6; ++j)
                *(float4*)(rv + 4 * j) = *(const float4*)&lr[SW(base + 4 * j)];
            #pragma unroll
            for (int ai = 0; ai < 2; ++ai) {
                const int dbase = cc * 256 + (slot * 2 + ai) * 8;
                float dk[8];
                *(float4*)(dk)     = *(const float4*)&ld[SW(dbase)];
                *(float4*)(dk + 4) = *(const float4*)&ld[SW(dbase + 4)];
                #pragma unroll
                for (int pi = 0; pi < 16; ++pi)
                    #pragma unroll
                    for (int kk = 0; kk < 8; ++kk)
                        acc[ai][pi] = fmaf(rv[pi + kk], dk[kk], acc[ai][pi]);
            }
        }
        __syncthreads();
    }

    // fm stores + per-row packed maxima
    u64 pm[2];
    #pragma unroll
    for (int ai = 0; ai < 2; ++ai) {
        const int row = a0 + slot * 2 + ai;
        float* outp = fm + ((long)b * A + row) * PW + p0;
        *(float4*)(outp)      = *(const float4*)&acc[ai][0];
        *(float4*)(outp + 4)  = *(const float4*)&acc[ai][4];
        *(float4*)(outp + 8)  = *(const float4*)&acc[ai][8];
        *(float4*)(outp + 12) = *(const float4*)&acc[ai][12];
        const unsigned rkey = (unsigned)(row * PW);
        u64 m = 0ull;
        #pragma unroll
        for (int i = 0; i < 16; ++i) {
            const u64 q = packmax21(acc[ai][i], rkey + p0 + i);
            if (q > m) m = q;
        }
        pm[ai] = m;
    }
    #pragma unroll
    for (int off = 1; off <= 8; off <<= 1) {
        #pragma unroll
        for (int ai = 0; ai < 2; ++ai) {
            u64 o = __shfl_xor(pm[ai], off);
            if (o > pm[ai]) pm[ai] = o;
        }
    }
    if (pg == 0) {
        #pragma unroll
        for (int ai = 0; ai < 2; ++ai) {
            const int row = a0 + slot * 2 + ai;
            u64 m = pm[ai];
            const u64 z = packmax21(0.0f, (unsigned)(row * PW) + 256);  // col 256 = 0
            if (z > m) m = z;
            rmax_g[(size_t)b * A + row] = m;
            rr[slot * 2 + ai] = m;
        }
    }
    __syncthreads();
    if (t < 2) {
        u64 m = rr[t * 16];
        #pragma unroll
        for (int i = 1; i < 16; ++i) if (rr[t * 16 + i] > m) m = rr[t * 16 + i];
        parts0[b * 256 + ck * 2 + t] = m;
    }
}

// ---------------- K5: one matching-pursuit iteration (one graph node) ----------------
__global__ __launch_bounds__(512) void k_step(const float* __restrict__ dn,
                                              float* __restrict__ recon,
                                              float* __restrict__ fm,
                                              u64* __restrict__ rmax_g,
                                              const u64* __restrict__ pin,
                                              u64* __restrict__ pout) {
    __shared__ __align__(16) float wpad[4][WROW];   // winner rows, stride-44 channels
    __shared__ float g[ATB][4][17];                 // Gram values (padded)
    __shared__ u64 rmax[4][ATB];
    __shared__ int sflag[64];
    __shared__ int   watom[4], wpos[4];
    __shared__ float wval[4];

    const int bk = blockIdx.x, a0 = bk * ATB, t = threadIdx.x;
    const int wv = t >> 6, ln = t & 63;
    const int a_ = t >> 5, tt = t & 31, bb_ = tt & 3, cg = tt >> 2;
    const int row = t >> 3, kk8 = t & 7, r_ai = row & 15, r_b = row >> 4;
    float* frow = fm + ((long)r_b * A + a0 + r_ai) * PW;
    const unsigned rkey = (unsigned)((a0 + r_ai) * PW);

    // own atom channels in registers: channel c = j*8+cg of atom a0+a_
    float own[8][8];
    {
        const float* s = dn + (long)(a0 + a_) * 512 + cg * 8;
        #pragma unroll
        for (int j = 0; j < 8; ++j) {
            *(float4*)&own[j][0] = *(const float4*)(s + j * 64);
            *(float4*)&own[j][4] = *(const float4*)(s + j * 64 + 4);
        }
    }
    // zero only the READ pad slots of wpad: words [0..8) and [16..24) per channel
    for (int i = t; i < 4 * 64 * 16; i += 512) {
        const int b = i >> 10, r = i & 1023, ch = r >> 4, w = r & 15;
        wpad[b][ch * WSTR + (w < 8 ? w : w + 8)] = 0.0f;
    }

    // ---- phase 1: winner reduce (waves 0-3) + rmax load (wave 4) ----
    if (wv < 4) {
        const u64* pb = pin + wv * 256 + ln * 4;
        u64 m0 = pb[0], m1 = pb[1], m2 = pb[2], m3 = pb[3];
        if (m1 > m0) m0 = m1;
        if (m3 > m2) m2 = m3;
        if (m2 > m0) m0 = m2;
        #pragma unroll
        for (int off = 1; off <= 32; off <<= 1) {
            u64 o = __shfl_xor(m0, off);
            if (o > m0) m0 = o;
        }
        if (ln == 0) decode21(m0, &watom[wv], &wpos[wv], &wval[wv]);
    } else if (wv == 4) {
        rmax[ln >> 4][ln & 15] = rmax_g[(size_t)(ln >> 4) * A + a0 + (ln & 15)];
    }
    __syncthreads();

    // ---- commit recon (blocks 4-7, b = bk-4) ----
    if (bk >= 4 && bk < 8) {
        const int b = bk - 4;
        const float cv = wval[b];
        const float* dw = dn + (long)watom[b] * 512;
        recon[(long)(b * C + (t >> 3)) * RC + wpos[b] + (t & 7)] += cv * dw[t];
    }

    // ---- write winner rows into wpad (data slots [8..15] of each 44-row) ----
    for (int i = t; i < 4 * 512; i += 512) {
        const int b = i >> 9, r = i & 511;
        wpad[b][(r >> 3) * WSTR + 8 + (r & 7)] = dn[(long)watom[b] * 512 + r];
    }
    __syncthreads();

    // ---- Gram: own (regs) x wpad -> g[a][bb][15] ----
    {
        float acc[15];
        #pragma unroll
        for (int i = 0; i < 15; ++i) acc[i] = 0.0f;
        #pragma unroll
        for (int j = 0; j < 8; ++j) {
            const float* wp = &wpad[bb_][(j * 8 + cg) * WSTR];
            float wr[24];
            *(float4*)(wr)      = *(const float4*)(wp);
            *(float4*)(wr + 4)  = *(const float4*)(wp + 4);
            *(float4*)(wr + 8)  = *(const float4*)(wp + 8);
            *(float4*)(wr + 12) = *(const float4*)(wp + 12);
            *(float4*)(wr + 16) = *(const float4*)(wp + 16);
            *(float4*)(wr + 20) = *(const float4*)(wp + 20);
            #pragma unroll
            for (int di = 0; di < 15; ++di)
                #pragma unroll
                for (int k = 0; k < 8; ++k)
                    acc[di] = fmaf(own[j][k], wr[15 + k - di], acc[di]);
        }
        #pragma unroll
        for (int di = 0; di < 15; ++di) {
            acc[di] += __shfl_xor(acc[di], 4);
            acc[di] += __shfl_xor(acc[di], 8);
            acc[di] += __shfl_xor(acc[di], 16);
        }
        if (cg == 0) {
            #pragma unroll
            for (int di = 0; di < 15; ++di) g[a_][bb_][di] = acc[di];
        }
    }
    __syncthreads();

    // ---- window update + winmax (8 threads per row) ----
    {
        const int q = wpos[r_b];
        const float val = wval[r_b];
        u64 wm = 0ull;
        #pragma unroll
        for (int h = 0; h < 2; ++h) {
            const int di = kk8 + h * 8;
            if (di < 15) {
                const int p = q + 7 - di;
                if (p >= 0 && p <= 256) {
                    const float nv = frow[p] - val * g[r_ai][r_b][di];
                    frow[p] = nv;
                    const u64 pm = packmax21(nv, rkey + p);
                    if (pm > wm) wm = pm;
                }
            }
        }
        #pragma unroll
        for (int off = 1; off <= 4; off <<= 1) {
            u64 o = __shfl_xor(wm, off);
            if (o > wm) wm = o;
        }
        if (kk8 == 0) {
            const u64 old = rmax[r_b][r_ai];
            const unsigned okey = 0x1FFFFFu - (unsigned)((old >> 11) & 0x1FFFFFu);
            const int opos = (int)(okey % PW);
            if (opos >= q - 7 && opos <= q + 7) {
                sflag[row] = 1;
            } else {
                sflag[row] = 0;
                rmax[r_b][r_ai] = (old > wm) ? old : wm;
            }
        }
    }
    __syncthreads();

    // ---- conditional full row rescan ----
    if (sflag[row]) {
        u64 m = 0ull;
        #pragma unroll
        for (int i = 0; i <= 8; ++i) {
            const int idx4 = kk8 + i * 8;
            if (idx4 < 65) {
                const float4 v = ((const float4*)frow)[idx4];
                const unsigned e = rkey + idx4 * 4;
                u64 q0 = packmax21(v.x, e);
                u64 q1 = packmax21(v.y, e + 1);
                u64 q2 = packmax21(v.z, e + 2);
                u64 q3 = packmax21(v.w, e + 3);
                if (q1 > q0) q0 = q1;
                if (q3 > q2) q2 = q3;
                if (q2 > q0) q0 = q2;
                if (q0 > m)  m = q0;
            }
        }
        #pragma unroll
        for (int off = 1; off <= 4; off <<= 1) {
            u64 o = __shfl_xor(m, off);
            if (o > m) m = o;
        }
        if (kk8 == 0) rmax[r_b][r_ai] = m;
    }
    __syncthreads();

    // ---- publish partials for next kernel + rmax write-back ----
    if (wv == 0) {
        const int b_ = ln >> 4, ai_ = ln & 15;
        u64 m = rmax[b_][ai_];
        #pragma unroll
        for (int off = 1; off <= 8; off <<= 1) {
            u64 o = __shfl_xor(m, off);
            if (o > m) m = o;
        }
        if (ai_ == 0) pout[b_ * 256 + bk] = m;
    } else if (wv == 1) {
        rmax_g[(size_t)(ln >> 4) * A + a0 + (ln & 15)] = rmax[ln >> 4][ln & 15];
    }
}

// ---------------- K6: final iteration — winner + commit + output copy ----------------
__global__ __launch_bounds__(512) void k_last(const float* __restrict__ dn,
                                              float* __restrict__ recon,
                                              const u64* __restrict__ pin,
                                              float* __restrict__ out) {
    __shared__ int s_atom, s_pos;
    __shared__ float s_val;
    const int b = blockIdx.x, t = threadIdx.x;
    const int wv = t >> 6, ln = t & 63;
    if (wv == 0) {
        const u64* pb = pin + b * 256 + ln * 4;
        u64 m0 = pb[0], m1 = pb[1], m2 = pb[2], m3 = pb[3];
        if (m1 > m0) m0 = m1;
        if (m3 > m2) m2 = m3;
        if (m2 > m0) m0 = m2;
        #pragma unroll
        for (int off = 1; off <= 32; off <<= 1) {
            u64 o = __shfl_xor(m0, off);
            if (o > m0) m0 = o;
        }
        if (ln == 0) decode21(m0, &s_atom, &s_pos, &s_val);
    }
    __syncthreads();
    recon[(long)(b * C + (t >> 3)) * RC + s_pos + (t & 7)] += s_val * dn[(long)s_atom * 512 + t];
    __syncthreads();
    for (int i = t; i < C * T / 4; i += 512) {
        const int c = i >> 6, t4 = i & 63;
        ((float4*)out)[b * 4096 + i] = *(const float4*)&recon[(long)(b * C + c) * RC + t4 * 4];
    }
}

extern "C" void kernel_launch(void* const* d_in, const int* in_sizes, int n_in,
                              void* d_out, int out_size, void* d_ws, size_t ws_size,
                              hipStream_t stream) {
    const float* x = (const float*)d_in[0];
    const float* d = (const float*)d_in[1];
    char* ws = (char*)d_ws;
    float* dn     = (float*)(ws + WS_DN);
    float* res    = (float*)(ws + WS_RES);
    float* recon  = (float*)(ws + WS_RECON);
    float* fm     = (float*)(ws + WS_FM);
    u64*   parts  = (u64*)(ws + WS_PARTS);
    u64*   rmax_g = (u64*)(ws + WS_RMAX);
    float* out    = (float*)d_out;
    u64* p0 = parts;
    u64* p1 = parts + 1024;

    hipLaunchKernelGGL(k_init, dim3(1024), dim3(256), 0, stream, x, d, dn, res, recon, fm);
    hipLaunchKernelGGL(k_conv, dim3(A / 32, B), dim3(256), 0, stream, res, dn, fm, rmax_g, p0);

    for (int it = 0; it < NITER - 1; ++it) {
        u64* pi = (it & 1) ? p1 : p0;
        u64* po = (it & 1) ? p0 : p1;
        hipLaunchKernelGGL(k_step, dim3(NBLK), dim3(512), 0, stream,
                           dn, recon, fm, rmax_g, pi, po);
    }
    // step 30 (even) wrote p1 — the final winner table
    hipLaunchKernelGGL(k_last, dim3(B), dim3(512), 0, stream, dn, recon, p1, out);
}